// Round 1
// baseline (711.200 us; speedup 1.0000x reference)
//
#include <hip/hip_runtime.h>
#include <math.h>

#define BSZ 4096
#define DIM 1024
#define NST 2900000

#define NCHUNK 16
#define ROWS_PER_CHUNK (BSZ / NCHUNK)   // 256

constexpr float GAMMA_S   = 0.8f;
constexpr float GAMMA_U   = 0.8f;
constexpr float RHO_I_C   = 0.1f;
constexpr float RHO_T_C   = 0.1f;
constexpr float C_EPS     = 1e-10f;
constexpr float TAU_MIN_C = 0.005f;
constexpr float TAU_MAX_C = 1.0f;
constexpr float GCLIP     = 5.0f;
constexpr float ETA_INIT_C = 0.01f;
constexpr float ETA_MIN_C  = 1e-4f;
constexpr float PI_F       = 3.14159265358979323846f;

// ---------------------------------------------------------------------------
// GEMM: sim[i][j] = sum_k A[i][k] * Bt[j][k]   (A, Bt row-major BSZ x DIM)
// 64x64 tile per block, 256 threads, 4x4 micro-tile per thread, BK=16.
// ---------------------------------------------------------------------------
__global__ __launch_bounds__(256) void gemm_nt(const float* __restrict__ A,
                                               const float* __restrict__ Bt,
                                               float* __restrict__ C) {
    __shared__ float As[16][64 + 4];
    __shared__ float Bs[16][64 + 4];
    const int tid = threadIdx.x;
    const int bi = blockIdx.y * 64;
    const int bj = blockIdx.x * 64;
    const int tx = tid & 15, ty = tid >> 4;
    const int lr = tid >> 2;          // 0..63 row within tile
    const int lk = (tid & 3) << 2;    // 0,4,8,12 k offset

    float acc[4][4] = {};

    for (int k0 = 0; k0 < DIM; k0 += 16) {
        float4 av = *(const float4*)&A[(size_t)(bi + lr) * DIM + k0 + lk];
        float4 bv = *(const float4*)&Bt[(size_t)(bj + lr) * DIM + k0 + lk];
        As[lk + 0][lr] = av.x; As[lk + 1][lr] = av.y;
        As[lk + 2][lr] = av.z; As[lk + 3][lr] = av.w;
        Bs[lk + 0][lr] = bv.x; Bs[lk + 1][lr] = bv.y;
        Bs[lk + 2][lr] = bv.z; Bs[lk + 3][lr] = bv.w;
        __syncthreads();
#pragma unroll
        for (int k = 0; k < 16; ++k) {
            float4 a = *(const float4*)&As[k][ty * 4];
            float4 b = *(const float4*)&Bs[k][tx * 4];
            float ar[4] = {a.x, a.y, a.z, a.w};
            float br[4] = {b.x, b.y, b.z, b.w};
#pragma unroll
            for (int m = 0; m < 4; ++m)
#pragma unroll
                for (int n = 0; n < 4; ++n)
                    acc[m][n] += ar[m] * br[n];
        }
        __syncthreads();
    }
#pragma unroll
    for (int m = 0; m < 4; ++m) {
        float4 v = make_float4(acc[m][0], acc[m][1], acc[m][2], acc[m][3]);
        *(float4*)&C[(size_t)(bi + ty * 4 + m) * BSZ + bj + tx * 4] = v;
    }
}

// ---------------------------------------------------------------------------
// Prep: gather diag, taus, old_b per batch position.
// ---------------------------------------------------------------------------
__global__ __launch_bounds__(256) void prep(const float* __restrict__ sim,
                                            const float* __restrict__ tau_I,
                                            const float* __restrict__ tau_T,
                                            const float* __restrict__ b_I,
                                            const float* __restrict__ b_T,
                                            const int* __restrict__ iid,
                                            const int* __restrict__ tid_,
                                            float* diag, float* tauIg, float* tauTg,
                                            float* obI, float* obT) {
    int i = blockIdx.x * 256 + threadIdx.x;
    if (i < BSZ) {
        diag[i]  = sim[(size_t)i * BSZ + i];
        tauIg[i] = tau_I[iid[i]];
        tauTg[i] = tau_T[tid_[i]];
        obI[i]   = b_I[iid[i]];
        obT[i]   = b_T[tid_[i]];
    }
}

// ---------------------------------------------------------------------------
// Row reduction (image side): per row i compute
//   b = max(max_j idt, old_b),  sumE = sum exp(idt-b),  sumEI = sum exp*idt
// ---------------------------------------------------------------------------
__global__ __launch_bounds__(256) void row_reduce(const float* __restrict__ sim,
                                                  const float* __restrict__ diag,
                                                  const float* __restrict__ tauIg,
                                                  const float* __restrict__ obI,
                                                  float* nbI, float* seI, float* seiI) {
    const int i = blockIdx.x;
    const float* row = sim + (size_t)i * BSZ;
    const float dg = diag[i];
    const float itau = 1.0f / tauIg[i];
    __shared__ float lds[8];

    float m = -INFINITY;
    for (int j = threadIdx.x; j < BSZ; j += 256)
        m = fmaxf(m, (row[j] - dg) * itau);
#pragma unroll
    for (int o = 32; o; o >>= 1) m = fmaxf(m, __shfl_down(m, o));
    const int wv = threadIdx.x >> 6, ln = threadIdx.x & 63;
    if (ln == 0) lds[wv] = m;
    __syncthreads();
    m = fmaxf(fmaxf(lds[0], lds[1]), fmaxf(lds[2], lds[3]));
    const float b = fmaxf(m, obI[i]);

    float se = 0.f, sei = 0.f;
    for (int j = threadIdx.x; j < BSZ; j += 256) {
        float v = (row[j] - dg) * itau;
        float e = expf(v - b);
        se += e;
        sei += e * v;
    }
#pragma unroll
    for (int o = 32; o; o >>= 1) {
        se += __shfl_down(se, o);
        sei += __shfl_down(sei, o);
    }
    __syncthreads();
    if (ln == 0) { lds[wv] = se; lds[4 + wv] = sei; }
    __syncthreads();
    if (threadIdx.x == 0) {
        nbI[i]  = b;
        seI[i]  = lds[0] + lds[1] + lds[2] + lds[3];
        seiI[i] = lds[4] + lds[5] + lds[6] + lds[7];
    }
}

// ---------------------------------------------------------------------------
// Column reduction stage 1: partial max per (row-chunk, column).
// Block = 64 cols x 4 row-lanes; grid = (BSZ/64, NCHUNK).
// ---------------------------------------------------------------------------
__global__ __launch_bounds__(256) void col_part1(const float* __restrict__ sim,
                                                 const float* __restrict__ diag,
                                                 const float* __restrict__ tauTg,
                                                 float* __restrict__ pmax) {
    const int ln = threadIdx.x & 63;
    const int w  = threadIdx.x >> 6;
    const int c  = blockIdx.x * 64 + ln;
    const float dg = diag[c];
    const float itau = 1.0f / tauTg[c];
    const int rbeg = blockIdx.y * ROWS_PER_CHUNK;

    float m = -INFINITY;
    for (int r = rbeg + w; r < rbeg + ROWS_PER_CHUNK; r += 4)
        m = fmaxf(m, (sim[(size_t)r * BSZ + c] - dg) * itau);

    __shared__ float lds[4][64];
    lds[w][ln] = m;
    __syncthreads();
    if (threadIdx.x < 64) {
        float mm = fmaxf(fmaxf(lds[0][threadIdx.x], lds[1][threadIdx.x]),
                         fmaxf(lds[2][threadIdx.x], lds[3][threadIdx.x]));
        pmax[blockIdx.y * BSZ + blockIdx.x * 64 + threadIdx.x] = mm;
    }
}

// ---------------------------------------------------------------------------
// Column reduction stage 2: combine maxes -> b, then partial sums with exp.
// ---------------------------------------------------------------------------
__global__ __launch_bounds__(256) void col_part2(const float* __restrict__ sim,
                                                 const float* __restrict__ diag,
                                                 const float* __restrict__ tauTg,
                                                 const float* __restrict__ obT,
                                                 const float* __restrict__ pmax,
                                                 float* nbT,
                                                 float* __restrict__ psE,
                                                 float* __restrict__ psEI) {
    const int ln = threadIdx.x & 63;
    const int w  = threadIdx.x >> 6;
    const int c  = blockIdx.x * 64 + ln;
    const float dg = diag[c];
    const float itau = 1.0f / tauTg[c];

    float b = obT[c];
#pragma unroll
    for (int k = 0; k < NCHUNK; ++k) b = fmaxf(b, pmax[k * BSZ + c]);
    if (blockIdx.y == 0 && w == 0) nbT[c] = b;

    const int rbeg = blockIdx.y * ROWS_PER_CHUNK;
    float se = 0.f, sei = 0.f;
    for (int r = rbeg + w; r < rbeg + ROWS_PER_CHUNK; r += 4) {
        float v = (sim[(size_t)r * BSZ + c] - dg) * itau;
        float e = expf(v - b);
        se += e;
        sei += e * v;
    }
    __shared__ float l1[4][64], l2[4][64];
    l1[w][ln] = se;
    l2[w][ln] = sei;
    __syncthreads();
    if (threadIdx.x < 64) {
        int t = threadIdx.x;
        psE [blockIdx.y * BSZ + blockIdx.x * 64 + t] = l1[0][t] + l1[1][t] + l1[2][t] + l1[3][t];
        psEI[blockIdx.y * BSZ + blockIdx.x * 64 + t] = l2[0][t] + l2[1][t] + l2[2][t] + l2[3][t];
    }
}

// ---------------------------------------------------------------------------
// Copy the 8 state arrays to the output region (out is re-poisoned each call).
// Output base is odd-offset (4*BSZ+3) so only 4B-aligned: scalar copies.
// ---------------------------------------------------------------------------
__global__ __launch_bounds__(256) void copy_states(const float* __restrict__ s_I,
                                                   const float* __restrict__ s_T,
                                                   const float* __restrict__ u_I,
                                                   const float* __restrict__ u_T,
                                                   const float* __restrict__ b_I,
                                                   const float* __restrict__ b_T,
                                                   const float* __restrict__ tau_I,
                                                   const float* __restrict__ tau_T,
                                                   float* __restrict__ outbase) {
    const size_t idx = (size_t)blockIdx.x * blockDim.x + threadIdx.x;
    const size_t stride = (size_t)gridDim.x * blockDim.x;
    const float* srcs[8] = {s_I, s_T, u_I, u_T, b_I, b_T, tau_I, tau_T};
#pragma unroll
    for (int a = 0; a < 8; ++a) {
        const float* s = srcs[a];
        float* d = outbase + (size_t)a * NST;
        for (size_t o = idx; o < NST; o += stride) d[o] = s[o];
    }
}

// ---------------------------------------------------------------------------
// Finalize: per batch position compute g, s_new, grad_tau, u_new, tau_new;
// write small outputs + scatter into the big arrays (after copy_states).
// ---------------------------------------------------------------------------
__global__ __launch_bounds__(256) void finalize(const float* __restrict__ s_I,
                                                const float* __restrict__ s_T,
                                                const float* __restrict__ u_I,
                                                const float* __restrict__ u_T,
                                                const int* __restrict__ iid,
                                                const int* __restrict__ tid_,
                                                const int* __restrict__ epoch,
                                                const int* __restrict__ maxep,
                                                const float* __restrict__ tauIg,
                                                const float* __restrict__ tauTg,
                                                const float* __restrict__ obI,
                                                const float* __restrict__ obT,
                                                const float* __restrict__ nbI,
                                                const float* __restrict__ nbT,
                                                const float* __restrict__ seI,
                                                const float* __restrict__ seiI,
                                                const float* __restrict__ psE,
                                                const float* __restrict__ psEI,
                                                float* __restrict__ out,
                                                float* __restrict__ ilo,
                                                float* __restrict__ tlo) {
    const int i = blockIdx.x * 256 + threadIdx.x;
    if (i >= BSZ) return;

    const float eta = ETA_MIN_C + (ETA_INIT_C - ETA_MIN_C) *
                      cosf(0.5f * PI_F * ((float)epoch[0] / (float)maxep[0]));
    const float invBm1 = 1.0f / (float)(BSZ - 1);

    float* o_gI   = out;
    float* o_gT   = out + BSZ;
    float* o_gti  = out + 2 * BSZ;
    float* o_gtt  = out + 3 * BSZ;
    float* o_sI   = out + 4 * BSZ + 3;
    float* o_sT   = o_sI + NST;
    float* o_uI   = o_sT + NST;
    float* o_uT   = o_uI + NST;
    float* o_bI   = o_uT + NST;
    float* o_bT   = o_bI + NST;
    float* o_tauI = o_bT + NST;
    float* o_tauT = o_tauI + NST;

    // image side
    {
        const int id = iid[i];
        const float g = seI[i] * invBm1;
        const float ob = obI[i], nb = nbI[i];
        const float s_new = (1.f - GAMMA_S) * s_I[id] * expf(ob - nb) + GAMMA_S * g;
        const float W = seiI[i] * invBm1 / (s_new + C_EPS);
        const float grad = logf(s_new) + nb + RHO_I_C - W;
        const float tau = tauIg[i];
        ilo[i] = tau * W;
        const float gc = fminf(fmaxf(grad, -GCLIP), GCLIP);
        const float u_new = (1.f - GAMMA_U) * u_I[id] + GAMMA_U * gc;
        const float tau_new = fminf(fmaxf(tau - eta * u_new, TAU_MIN_C), TAU_MAX_C);
        o_gI[i] = g;
        o_gti[i] = grad;
        o_sI[id] = s_new;
        o_uI[id] = u_new;
        o_bI[id] = nb;
        o_tauI[id] = tau_new;
    }
    // text side
    {
        const int id = tid_[i];
        float se = 0.f, sei = 0.f;
#pragma unroll
        for (int k = 0; k < NCHUNK; ++k) {
            se += psE[k * BSZ + i];
            sei += psEI[k * BSZ + i];
        }
        const float g = se * invBm1;
        const float ob = obT[i], nb = nbT[i];
        const float s_new = (1.f - GAMMA_S) * s_T[id] * expf(ob - nb) + GAMMA_S * g;
        const float W = sei * invBm1 / (s_new + C_EPS);
        const float grad = logf(s_new) + nb + RHO_T_C - W;
        const float tau = tauTg[i];
        tlo[i] = tau * W;
        const float gc = fminf(fmaxf(grad, -GCLIP), GCLIP);
        const float u_new = (1.f - GAMMA_U) * u_T[id] + GAMMA_U * gc;
        const float tau_new = fminf(fmaxf(tau - eta * u_new, TAU_MIN_C), TAU_MAX_C);
        o_gT[i] = g;
        o_gtt[i] = grad;
        o_sT[id] = s_new;
        o_uT[id] = u_new;
        o_bT[id] = nb;
        o_tauT[id] = tau_new;
    }
}

// ---------------------------------------------------------------------------
// Scalars: total_loss, avg taus.
// ---------------------------------------------------------------------------
__global__ __launch_bounds__(256) void scalar_out(const float* __restrict__ ilo,
                                                  const float* __restrict__ tlo,
                                                  const float* __restrict__ tauIg,
                                                  const float* __restrict__ tauTg,
                                                  float* __restrict__ out) {
    float s0 = 0.f, s1 = 0.f, s2 = 0.f, s3 = 0.f;
    for (int j = threadIdx.x; j < BSZ; j += 256) {
        s0 += ilo[j];
        s1 += tlo[j];
        s2 += tauIg[j];
        s3 += tauTg[j];
    }
#pragma unroll
    for (int o = 32; o; o >>= 1) {
        s0 += __shfl_down(s0, o);
        s1 += __shfl_down(s1, o);
        s2 += __shfl_down(s2, o);
        s3 += __shfl_down(s3, o);
    }
    __shared__ float lds[4][4];
    const int wv = threadIdx.x >> 6, ln = threadIdx.x & 63;
    if (ln == 0) { lds[wv][0] = s0; lds[wv][1] = s1; lds[wv][2] = s2; lds[wv][3] = s3; }
    __syncthreads();
    if (threadIdx.x == 0) {
        float t0 = lds[0][0] + lds[1][0] + lds[2][0] + lds[3][0];
        float t1 = lds[0][1] + lds[1][1] + lds[2][1] + lds[3][1];
        float t2 = lds[0][2] + lds[1][2] + lds[2][2] + lds[3][2];
        float t3 = lds[0][3] + lds[1][3] + lds[2][3] + lds[3][3];
        out[4 * BSZ + 0] = t0 / BSZ + t1 / BSZ;
        out[4 * BSZ + 1] = t2 / BSZ;
        out[4 * BSZ + 2] = t3 / BSZ;
    }
}

// ---------------------------------------------------------------------------
extern "C" void kernel_launch(void* const* d_in, const int* in_sizes, int n_in,
                              void* d_out, int out_size, void* d_ws, size_t ws_size,
                              hipStream_t stream) {
    const float* imf   = (const float*)d_in[0];
    const float* txf   = (const float*)d_in[1];
    const float* s_I   = (const float*)d_in[2];
    const float* s_T   = (const float*)d_in[3];
    const float* tau_I = (const float*)d_in[4];
    const float* tau_T = (const float*)d_in[5];
    const float* u_I   = (const float*)d_in[6];
    const float* u_T   = (const float*)d_in[7];
    const float* b_I   = (const float*)d_in[8];
    const float* b_T   = (const float*)d_in[9];
    const int* iid     = (const int*)d_in[10];
    const int* tid_    = (const int*)d_in[11];
    const int* epoch   = (const int*)d_in[12];
    const int* maxep   = (const int*)d_in[13];

    float* out = (float*)d_out;
    float* ws  = (float*)d_ws;

    float* sim  = ws;
    float* aux  = ws + (size_t)BSZ * BSZ;
    float* diag  = aux + 0 * BSZ;
    float* tauIg = aux + 1 * BSZ;
    float* tauTg = aux + 2 * BSZ;
    float* obI   = aux + 3 * BSZ;
    float* obT   = aux + 4 * BSZ;
    float* nbI   = aux + 5 * BSZ;
    float* nbT   = aux + 6 * BSZ;
    float* seI   = aux + 7 * BSZ;
    float* seiI  = aux + 8 * BSZ;
    float* ilo   = aux + 9 * BSZ;
    float* tlo   = aux + 10 * BSZ;
    float* pmax  = aux + 11 * BSZ;                 // NCHUNK * BSZ
    float* psE   = pmax + (size_t)NCHUNK * BSZ;    // NCHUNK * BSZ
    float* psEI  = psE + (size_t)NCHUNK * BSZ;     // NCHUNK * BSZ

    dim3 gg(BSZ / 64, BSZ / 64);
    gemm_nt<<<gg, 256, 0, stream>>>(imf, txf, sim);
    prep<<<BSZ / 256, 256, 0, stream>>>(sim, tau_I, tau_T, b_I, b_T, iid, tid_,
                                        diag, tauIg, tauTg, obI, obT);
    row_reduce<<<BSZ, 256, 0, stream>>>(sim, diag, tauIg, obI, nbI, seI, seiI);
    col_part1<<<dim3(BSZ / 64, NCHUNK), 256, 0, stream>>>(sim, diag, tauTg, pmax);
    col_part2<<<dim3(BSZ / 64, NCHUNK), 256, 0, stream>>>(sim, diag, tauTg, obT,
                                                          pmax, nbT, psE, psEI);
    copy_states<<<4096, 256, 0, stream>>>(s_I, s_T, u_I, u_T, b_I, b_T, tau_I, tau_T,
                                          out + 4 * BSZ + 3);
    finalize<<<BSZ / 256, 256, 0, stream>>>(s_I, s_T, u_I, u_T, iid, tid_, epoch, maxep,
                                            tauIg, tauTg, obI, obT, nbI, nbT,
                                            seI, seiI, psE, psEI, out, ilo, tlo);
    scalar_out<<<1, 256, 0, stream>>>(ilo, tlo, tauIg, tauTg, out);
}

// Round 2
// 347.170 us; speedup vs baseline: 2.0486x; 2.0486x over previous
//
#include <hip/hip_runtime.h>
#include <math.h>

#define BSZ 4096
#define DIM 1024
#define NST 2900000

#define NCHUNK 16
#define ROWS_PER_CHUNK (BSZ / NCHUNK)   // 256

constexpr float GAMMA_S   = 0.8f;
constexpr float GAMMA_U   = 0.8f;
constexpr float RHO_I_C   = 0.1f;
constexpr float RHO_T_C   = 0.1f;
constexpr float C_EPS     = 1e-10f;
constexpr float TAU_MIN_C = 0.005f;
constexpr float TAU_MAX_C = 1.0f;
constexpr float GCLIP     = 5.0f;
constexpr float ETA_INIT_C = 0.01f;
constexpr float ETA_MIN_C  = 1e-4f;
constexpr float PI_F       = 3.14159265358979323846f;

typedef __bf16 bf16x8 __attribute__((ext_vector_type(8)));
typedef float  f32x4  __attribute__((ext_vector_type(4)));

// ---------------------------------------------------------------------------
// fp32 -> bf16 (RNE) conversion of both feature matrices.
// ---------------------------------------------------------------------------
__device__ __forceinline__ unsigned short f2bf(float f) {
    unsigned int u = __float_as_uint(f);
    u += 0x7fffu + ((u >> 16) & 1u);
    return (unsigned short)(u >> 16);
}

__global__ __launch_bounds__(256) void convert_bf16(const float* __restrict__ imf,
                                                    const float* __restrict__ txf,
                                                    unsigned short* __restrict__ a,
                                                    unsigned short* __restrict__ b) {
    const size_t i = ((size_t)blockIdx.x * 256 + threadIdx.x) * 4;
    if (i >= (size_t)BSZ * DIM) return;
    float4 va = *(const float4*)&imf[i];
    float4 vb = *(const float4*)&txf[i];
    ushort4 ra, rb;
    ra.x = f2bf(va.x); ra.y = f2bf(va.y); ra.z = f2bf(va.z); ra.w = f2bf(va.w);
    rb.x = f2bf(vb.x); rb.y = f2bf(vb.y); rb.z = f2bf(vb.z); rb.w = f2bf(vb.w);
    *(ushort4*)&a[i] = ra;
    *(ushort4*)&b[i] = rb;
}

// ---------------------------------------------------------------------------
// bf16 MFMA GEMM (m97 structure): sim[i][j] = sum_k A[i][k]*B[j][k], fp32 out.
// 128x128 tile / block, 256 threads (4 waves), each wave 64x64 as 4x4 MFMA
// 16x16x32 tiles. global_load_lds width=16 staging, BK=32.
// ---------------------------------------------------------------------------
__device__ __forceinline__ void async16(const void* g, void* l) {
    __builtin_amdgcn_global_load_lds(
        (const __attribute__((address_space(1))) void*)g,
        (__attribute__((address_space(3))) void*)l, 16, 0, 0);
}

__global__ __launch_bounds__(256) void gemm_bt_bf16(const unsigned short* __restrict__ A,
                                                    const unsigned short* __restrict__ B,
                                                    float* __restrict__ C) {
    __shared__ unsigned short As[128 * 32];   // row-major [128][32] bf16, 8 KB
    __shared__ unsigned short Bs[128 * 32];

    const int tid  = threadIdx.x;
    const int lane = tid & 63;
    const int wave = tid >> 6;
    const int bi = blockIdx.y * 128;
    const int bj = blockIdx.x * 128;
    const int m_base = (wave >> 1) * 64;
    const int n_base = (wave & 1) * 64;

    // staging chunk mapping: chunk c (16B) -> row c>>2, k-offset (c&3)*8.
    // LDS dest = contiguous chunks => wave-uniform base + lane*16.  [m104 rule]
    const int c0 = tid, c1 = tid + 256;
    const int r0 = c0 >> 2, ko0 = (c0 & 3) * 8;
    const int r1 = c1 >> 2, ko1 = (c1 & 3) * 8;

    f32x4 acc[4][4];
#pragma unroll
    for (int m = 0; m < 4; ++m)
#pragma unroll
        for (int n = 0; n < 4; ++n)
            acc[m][n] = (f32x4){0.f, 0.f, 0.f, 0.f};

    const int mrow = lane & 15;
    const int kq   = (lane >> 4) * 8;

    for (int k0 = 0; k0 < DIM; k0 += 32) {
        __syncthreads();   // protect LDS still being read by previous iter
        async16(&A[(size_t)(bi + r0) * DIM + k0 + ko0], &As[c0 * 8]);
        async16(&A[(size_t)(bi + r1) * DIM + k0 + ko1], &As[c1 * 8]);
        async16(&B[(size_t)(bj + r0) * DIM + k0 + ko0], &Bs[c0 * 8]);
        async16(&B[(size_t)(bj + r1) * DIM + k0 + ko1], &Bs[c1 * 8]);
        __syncthreads();   // compiler drains vmcnt before s_barrier

        bf16x8 af[4], bfr[4];
#pragma unroll
        for (int t = 0; t < 4; ++t) {
            af[t]  = *(const bf16x8*)&As[(m_base + t * 16 + mrow) * 32 + kq];
            bfr[t] = *(const bf16x8*)&Bs[(n_base + t * 16 + mrow) * 32 + kq];
        }
#pragma unroll
        for (int mt = 0; mt < 4; ++mt)
#pragma unroll
            for (int nt = 0; nt < 4; ++nt)
                acc[mt][nt] = __builtin_amdgcn_mfma_f32_16x16x32_bf16(
                    af[mt], bfr[nt], acc[mt][nt], 0, 0, 0);
    }

    // C/D layout: col = lane&15, row = (lane>>4)*4 + r   [m89 verified]
    const int col  = lane & 15;
    const int rowq = (lane >> 4) * 4;
#pragma unroll
    for (int mt = 0; mt < 4; ++mt)
#pragma unroll
        for (int nt = 0; nt < 4; ++nt)
#pragma unroll
            for (int r = 0; r < 4; ++r)
                C[(size_t)(bi + m_base + mt * 16 + rowq + r) * BSZ +
                  bj + n_base + nt * 16 + col] = acc[mt][nt][r];
}

// ---------------------------------------------------------------------------
// Prep: gather diag, taus, old_b per batch position.
// ---------------------------------------------------------------------------
__global__ __launch_bounds__(256) void prep(const float* __restrict__ sim,
                                            const float* __restrict__ tau_I,
                                            const float* __restrict__ tau_T,
                                            const float* __restrict__ b_I,
                                            const float* __restrict__ b_T,
                                            const int* __restrict__ iid,
                                            const int* __restrict__ tid_,
                                            float* diag, float* tauIg, float* tauTg,
                                            float* obI, float* obT) {
    int i = blockIdx.x * 256 + threadIdx.x;
    if (i < BSZ) {
        diag[i]  = sim[(size_t)i * BSZ + i];
        tauIg[i] = tau_I[iid[i]];
        tauTg[i] = tau_T[tid_[i]];
        obI[i]   = b_I[iid[i]];
        obT[i]   = b_T[tid_[i]];
    }
}

// ---------------------------------------------------------------------------
// Row reduction (image side).
// ---------------------------------------------------------------------------
__global__ __launch_bounds__(256) void row_reduce(const float* __restrict__ sim,
                                                  const float* __restrict__ diag,
                                                  const float* __restrict__ tauIg,
                                                  const float* __restrict__ obI,
                                                  float* nbI, float* seI, float* seiI) {
    const int i = blockIdx.x;
    const float* row = sim + (size_t)i * BSZ;
    const float dg = diag[i];
    const float itau = 1.0f / tauIg[i];
    __shared__ float lds[8];

    float m = -INFINITY;
    for (int j = threadIdx.x; j < BSZ; j += 256)
        m = fmaxf(m, (row[j] - dg) * itau);
#pragma unroll
    for (int o = 32; o; o >>= 1) m = fmaxf(m, __shfl_down(m, o));
    const int wv = threadIdx.x >> 6, ln = threadIdx.x & 63;
    if (ln == 0) lds[wv] = m;
    __syncthreads();
    m = fmaxf(fmaxf(lds[0], lds[1]), fmaxf(lds[2], lds[3]));
    const float b = fmaxf(m, obI[i]);

    float se = 0.f, sei = 0.f;
    for (int j = threadIdx.x; j < BSZ; j += 256) {
        float v = (row[j] - dg) * itau;
        float e = expf(v - b);
        se += e;
        sei += e * v;
    }
#pragma unroll
    for (int o = 32; o; o >>= 1) {
        se += __shfl_down(se, o);
        sei += __shfl_down(sei, o);
    }
    __syncthreads();
    if (ln == 0) { lds[wv] = se; lds[4 + wv] = sei; }
    __syncthreads();
    if (threadIdx.x == 0) {
        nbI[i]  = b;
        seI[i]  = lds[0] + lds[1] + lds[2] + lds[3];
        seiI[i] = lds[4] + lds[5] + lds[6] + lds[7];
    }
}

// ---------------------------------------------------------------------------
// Column reduction stage 1: partial max per (row-chunk, column).
// ---------------------------------------------------------------------------
__global__ __launch_bounds__(256) void col_part1(const float* __restrict__ sim,
                                                 const float* __restrict__ diag,
                                                 const float* __restrict__ tauTg,
                                                 float* __restrict__ pmax) {
    const int ln = threadIdx.x & 63;
    const int w  = threadIdx.x >> 6;
    const int c  = blockIdx.x * 64 + ln;
    const float dg = diag[c];
    const float itau = 1.0f / tauTg[c];
    const int rbeg = blockIdx.y * ROWS_PER_CHUNK;

    float m = -INFINITY;
    for (int r = rbeg + w; r < rbeg + ROWS_PER_CHUNK; r += 4)
        m = fmaxf(m, (sim[(size_t)r * BSZ + c] - dg) * itau);

    __shared__ float lds[4][64];
    lds[w][ln] = m;
    __syncthreads();
    if (threadIdx.x < 64) {
        float mm = fmaxf(fmaxf(lds[0][threadIdx.x], lds[1][threadIdx.x]),
                         fmaxf(lds[2][threadIdx.x], lds[3][threadIdx.x]));
        pmax[blockIdx.y * BSZ + blockIdx.x * 64 + threadIdx.x] = mm;
    }
}

// ---------------------------------------------------------------------------
// Column reduction stage 2: combine maxes -> b, then partial sums with exp.
// ---------------------------------------------------------------------------
__global__ __launch_bounds__(256) void col_part2(const float* __restrict__ sim,
                                                 const float* __restrict__ diag,
                                                 const float* __restrict__ tauTg,
                                                 const float* __restrict__ obT,
                                                 const float* __restrict__ pmax,
                                                 float* nbT,
                                                 float* __restrict__ psE,
                                                 float* __restrict__ psEI) {
    const int ln = threadIdx.x & 63;
    const int w  = threadIdx.x >> 6;
    const int c  = blockIdx.x * 64 + ln;
    const float dg = diag[c];
    const float itau = 1.0f / tauTg[c];

    float b = obT[c];
#pragma unroll
    for (int k = 0; k < NCHUNK; ++k) b = fmaxf(b, pmax[k * BSZ + c]);
    if (blockIdx.y == 0 && w == 0) nbT[c] = b;

    const int rbeg = blockIdx.y * ROWS_PER_CHUNK;
    float se = 0.f, sei = 0.f;
    for (int r = rbeg + w; r < rbeg + ROWS_PER_CHUNK; r += 4) {
        float v = (sim[(size_t)r * BSZ + c] - dg) * itau;
        float e = expf(v - b);
        se += e;
        sei += e * v;
    }
    __shared__ float l1[4][64], l2[4][64];
    l1[w][ln] = se;
    l2[w][ln] = sei;
    __syncthreads();
    if (threadIdx.x < 64) {
        int t = threadIdx.x;
        psE [blockIdx.y * BSZ + blockIdx.x * 64 + t] = l1[0][t] + l1[1][t] + l1[2][t] + l1[3][t];
        psEI[blockIdx.y * BSZ + blockIdx.x * 64 + t] = l2[0][t] + l2[1][t] + l2[2][t] + l2[3][t];
    }
}

// ---------------------------------------------------------------------------
// Copy 8 state arrays to output region. dst base = out + 16387 (odd offset);
// skipping 1 head element makes float-offset % 4 == 0 (NST % 4 == 0) ->
// aligned float4 stores.  Loads are element-offset 1 mod 4: scalar, L1-cached.
// ---------------------------------------------------------------------------
__global__ __launch_bounds__(256) void copy_states(const float* __restrict__ s_I,
                                                   const float* __restrict__ s_T,
                                                   const float* __restrict__ u_I,
                                                   const float* __restrict__ u_T,
                                                   const float* __restrict__ b_I,
                                                   const float* __restrict__ b_T,
                                                   const float* __restrict__ tau_I,
                                                   const float* __restrict__ tau_T,
                                                   float* __restrict__ outbase) {
    const size_t idx = (size_t)blockIdx.x * blockDim.x + threadIdx.x;
    const size_t stride = (size_t)gridDim.x * blockDim.x;
    const size_t NV = (NST - 1) / 4;           // 724999 full float4 chunks
    const float* srcs[8] = {s_I, s_T, u_I, u_T, b_I, b_T, tau_I, tau_T};
#pragma unroll
    for (int a = 0; a < 8; ++a) {
        const float* s = srcs[a];
        float* d = outbase + (size_t)a * NST;
        for (size_t c = idx; c < NV; c += stride) {
            const size_t e = 1 + 4 * c;
            float4 v = make_float4(s[e], s[e + 1], s[e + 2], s[e + 3]);
            *(float4*)&d[e] = v;
        }
        if (idx == 0) d[0] = s[0];
        if (idx < 3)  d[NST - 3 + idx] = s[NST - 3 + idx];
    }
}

// ---------------------------------------------------------------------------
// Finalize: per batch position compute g, s_new, grad_tau, u_new, tau_new.
// ---------------------------------------------------------------------------
__global__ __launch_bounds__(256) void finalize(const float* __restrict__ s_I,
                                                const float* __restrict__ s_T,
                                                const float* __restrict__ u_I,
                                                const float* __restrict__ u_T,
                                                const int* __restrict__ iid,
                                                const int* __restrict__ tid_,
                                                const int* __restrict__ epoch,
                                                const int* __restrict__ maxep,
                                                const float* __restrict__ tauIg,
                                                const float* __restrict__ tauTg,
                                                const float* __restrict__ obI,
                                                const float* __restrict__ obT,
                                                const float* __restrict__ nbI,
                                                const float* __restrict__ nbT,
                                                const float* __restrict__ seI,
                                                const float* __restrict__ seiI,
                                                const float* __restrict__ psE,
                                                const float* __restrict__ psEI,
                                                float* __restrict__ out,
                                                float* __restrict__ ilo,
                                                float* __restrict__ tlo) {
    const int i = blockIdx.x * 256 + threadIdx.x;
    if (i >= BSZ) return;

    const float eta = ETA_MIN_C + (ETA_INIT_C - ETA_MIN_C) *
                      cosf(0.5f * PI_F * ((float)epoch[0] / (float)maxep[0]));
    const float invBm1 = 1.0f / (float)(BSZ - 1);

    float* o_gI   = out;
    float* o_gT   = out + BSZ;
    float* o_gti  = out + 2 * BSZ;
    float* o_gtt  = out + 3 * BSZ;
    float* o_sI   = out + 4 * BSZ + 3;
    float* o_sT   = o_sI + NST;
    float* o_uI   = o_sT + NST;
    float* o_uT   = o_uI + NST;
    float* o_bI   = o_uT + NST;
    float* o_bT   = o_bI + NST;
    float* o_tauI = o_bT + NST;
    float* o_tauT = o_tauI + NST;

    // image side
    {
        const int id = iid[i];
        const float g = seI[i] * invBm1;
        const float ob = obI[i], nb = nbI[i];
        const float s_new = (1.f - GAMMA_S) * s_I[id] * expf(ob - nb) + GAMMA_S * g;
        const float W = seiI[i] * invBm1 / (s_new + C_EPS);
        const float grad = logf(s_new) + nb + RHO_I_C - W;
        const float tau = tauIg[i];
        ilo[i] = tau * W;
        const float gc = fminf(fmaxf(grad, -GCLIP), GCLIP);
        const float u_new = (1.f - GAMMA_U) * u_I[id] + GAMMA_U * gc;
        const float tau_new = fminf(fmaxf(tau - eta * u_new, TAU_MIN_C), TAU_MAX_C);
        o_gI[i] = g;
        o_gti[i] = grad;
        o_sI[id] = s_new;
        o_uI[id] = u_new;
        o_bI[id] = nb;
        o_tauI[id] = tau_new;
    }
    // text side
    {
        const int id = tid_[i];
        float se = 0.f, sei = 0.f;
#pragma unroll
        for (int k = 0; k < NCHUNK; ++k) {
            se += psE[k * BSZ + i];
            sei += psEI[k * BSZ + i];
        }
        const float g = se * invBm1;
        const float ob = obT[i], nb = nbT[i];
        const float s_new = (1.f - GAMMA_S) * s_T[id] * expf(ob - nb) + GAMMA_S * g;
        const float W = sei * invBm1 / (s_new + C_EPS);
        const float grad = logf(s_new) + nb + RHO_T_C - W;
        const float tau = tauTg[i];
        tlo[i] = tau * W;
        const float gc = fminf(fmaxf(grad, -GCLIP), GCLIP);
        const float u_new = (1.f - GAMMA_U) * u_T[id] + GAMMA_U * gc;
        const float tau_new = fminf(fmaxf(tau - eta * u_new, TAU_MIN_C), TAU_MAX_C);
        o_gT[i] = g;
        o_gtt[i] = grad;
        o_sT[id] = s_new;
        o_uT[id] = u_new;
        o_bT[id] = nb;
        o_tauT[id] = tau_new;
    }
}

// ---------------------------------------------------------------------------
// Scalars: total_loss, avg taus.
// ---------------------------------------------------------------------------
__global__ __launch_bounds__(256) void scalar_out(const float* __restrict__ ilo,
                                                  const float* __restrict__ tlo,
                                                  const float* __restrict__ tauIg,
                                                  const float* __restrict__ tauTg,
                                                  float* __restrict__ out) {
    float s0 = 0.f, s1 = 0.f, s2 = 0.f, s3 = 0.f;
    for (int j = threadIdx.x; j < BSZ; j += 256) {
        s0 += ilo[j];
        s1 += tlo[j];
        s2 += tauIg[j];
        s3 += tauTg[j];
    }
#pragma unroll
    for (int o = 32; o; o >>= 1) {
        s0 += __shfl_down(s0, o);
        s1 += __shfl_down(s1, o);
        s2 += __shfl_down(s2, o);
        s3 += __shfl_down(s3, o);
    }
    __shared__ float lds[4][4];
    const int wv = threadIdx.x >> 6, ln = threadIdx.x & 63;
    if (ln == 0) { lds[wv][0] = s0; lds[wv][1] = s1; lds[wv][2] = s2; lds[wv][3] = s3; }
    __syncthreads();
    if (threadIdx.x == 0) {
        float t0 = lds[0][0] + lds[1][0] + lds[2][0] + lds[3][0];
        float t1 = lds[0][1] + lds[1][1] + lds[2][1] + lds[3][1];
        float t2 = lds[0][2] + lds[1][2] + lds[2][2] + lds[3][2];
        float t3 = lds[0][3] + lds[1][3] + lds[2][3] + lds[3][3];
        out[4 * BSZ + 0] = t0 / BSZ + t1 / BSZ;
        out[4 * BSZ + 1] = t2 / BSZ;
        out[4 * BSZ + 2] = t3 / BSZ;
    }
}

// ---------------------------------------------------------------------------
extern "C" void kernel_launch(void* const* d_in, const int* in_sizes, int n_in,
                              void* d_out, int out_size, void* d_ws, size_t ws_size,
                              hipStream_t stream) {
    const float* imf   = (const float*)d_in[0];
    const float* txf   = (const float*)d_in[1];
    const float* s_I   = (const float*)d_in[2];
    const float* s_T   = (const float*)d_in[3];
    const float* tau_I = (const float*)d_in[4];
    const float* tau_T = (const float*)d_in[5];
    const float* u_I   = (const float*)d_in[6];
    const float* u_T   = (const float*)d_in[7];
    const float* b_I   = (const float*)d_in[8];
    const float* b_T   = (const float*)d_in[9];
    const int* iid     = (const int*)d_in[10];
    const int* tid_    = (const int*)d_in[11];
    const int* epoch   = (const int*)d_in[12];
    const int* maxep   = (const int*)d_in[13];

    float* out = (float*)d_out;
    float* ws  = (float*)d_ws;

    float* sim  = ws;
    float* aux  = ws + (size_t)BSZ * BSZ;
    float* diag  = aux + 0 * BSZ;
    float* tauIg = aux + 1 * BSZ;
    float* tauTg = aux + 2 * BSZ;
    float* obI   = aux + 3 * BSZ;
    float* obT   = aux + 4 * BSZ;
    float* nbI   = aux + 5 * BSZ;
    float* nbT   = aux + 6 * BSZ;
    float* seI   = aux + 7 * BSZ;
    float* seiI  = aux + 8 * BSZ;
    float* ilo   = aux + 9 * BSZ;
    float* tlo   = aux + 10 * BSZ;
    float* pmax  = aux + 11 * BSZ;                 // NCHUNK * BSZ
    float* psE   = pmax + (size_t)NCHUNK * BSZ;    // NCHUNK * BSZ
    float* psEI  = psE + (size_t)NCHUNK * BSZ;     // NCHUNK * BSZ
    unsigned short* abf = (unsigned short*)(psEI + (size_t)NCHUNK * BSZ);  // BSZ*DIM bf16
    unsigned short* bbf = abf + (size_t)BSZ * DIM;                          // BSZ*DIM bf16

    convert_bf16<<<(BSZ * DIM / 4 + 255) / 256, 256, 0, stream>>>(imf, txf, abf, bbf);
    dim3 gg(BSZ / 128, BSZ / 128);
    gemm_bt_bf16<<<gg, 256, 0, stream>>>(abf, bbf, sim);
    prep<<<BSZ / 256, 256, 0, stream>>>(sim, tau_I, tau_T, b_I, b_T, iid, tid_,
                                        diag, tauIg, tauTg, obI, obT);
    row_reduce<<<BSZ, 256, 0, stream>>>(sim, diag, tauIg, obI, nbI, seI, seiI);
    col_part1<<<dim3(BSZ / 64, NCHUNK), 256, 0, stream>>>(sim, diag, tauTg, pmax);
    col_part2<<<dim3(BSZ / 64, NCHUNK), 256, 0, stream>>>(sim, diag, tauTg, obT,
                                                          pmax, nbT, psE, psEI);
    copy_states<<<4096, 256, 0, stream>>>(s_I, s_T, u_I, u_T, b_I, b_T, tau_I, tau_T,
                                          out + 4 * BSZ + 3);
    finalize<<<BSZ / 256, 256, 0, stream>>>(s_I, s_T, u_I, u_T, iid, tid_, epoch, maxep,
                                            tauIg, tauTg, obI, obT, nbI, nbT,
                                            seI, seiI, psE, psEI, out, ilo, tlo);
    scalar_out<<<1, 256, 0, stream>>>(ilo, tlo, tauIg, tauTg, out);
}

// Round 3
// 344.671 us; speedup vs baseline: 2.0634x; 1.0073x over previous
//
#include <hip/hip_runtime.h>
#include <math.h>

#define BSZ 4096
#define DIM 1024
#define NST 2900000

constexpr float GAMMA_S   = 0.8f;
constexpr float GAMMA_U   = 0.8f;
constexpr float RHO_I_C   = 0.1f;
constexpr float RHO_T_C   = 0.1f;
constexpr float C_EPS     = 1e-10f;
constexpr float TAU_MIN_C = 0.005f;
constexpr float TAU_MAX_C = 1.0f;
constexpr float GCLIP     = 5.0f;
constexpr float ETA_INIT_C = 0.01f;
constexpr float ETA_MIN_C  = 1e-4f;
constexpr float PI_F       = 3.14159265358979323846f;

typedef __bf16 bf16x8 __attribute__((ext_vector_type(8)));
typedef float  f32x4  __attribute__((ext_vector_type(4)));

__device__ __forceinline__ unsigned short f2bf(float f) {
    unsigned int u = __float_as_uint(f);
    u += 0x7fffu + ((u >> 16) & 1u);
    return (unsigned short)(u >> 16);
}
__device__ __forceinline__ float bf2f(unsigned short s) {
    return __uint_as_float(((unsigned int)s) << 16);
}

// ---------------------------------------------------------------------------
// conv_diag: fp32->bf16 both feature matrices + bf16-consistent diag dot +
// gather taus/old_b.  One wave per row, 4 rows per block.
// ---------------------------------------------------------------------------
__global__ __launch_bounds__(256) void conv_diag(const float* __restrict__ imf,
                                                 const float* __restrict__ txf,
                                                 unsigned short* __restrict__ abf,
                                                 unsigned short* __restrict__ bbf,
                                                 const float* __restrict__ tau_I,
                                                 const float* __restrict__ tau_T,
                                                 const float* __restrict__ b_I,
                                                 const float* __restrict__ b_T,
                                                 const int* __restrict__ iid,
                                                 const int* __restrict__ tid_,
                                                 float* diag, float* tauIg, float* tauTg,
                                                 float* obI, float* obT) {
    const int w  = threadIdx.x >> 6;
    const int ln = threadIdx.x & 63;
    const int i  = blockIdx.x * 4 + w;          // row
    float dot = 0.f;
#pragma unroll
    for (int k = 0; k < 4; ++k) {
        const int off = i * DIM + k * 256 + ln * 4;
        float4 a = *(const float4*)&imf[off];
        float4 b = *(const float4*)&txf[off];
        ushort4 ra, rb;
        ra.x = f2bf(a.x); ra.y = f2bf(a.y); ra.z = f2bf(a.z); ra.w = f2bf(a.w);
        rb.x = f2bf(b.x); rb.y = f2bf(b.y); rb.z = f2bf(b.z); rb.w = f2bf(b.w);
        *(ushort4*)&abf[off] = ra;
        *(ushort4*)&bbf[off] = rb;
        dot += bf2f(ra.x) * bf2f(rb.x) + bf2f(ra.y) * bf2f(rb.y) +
               bf2f(ra.z) * bf2f(rb.z) + bf2f(ra.w) * bf2f(rb.w);
    }
#pragma unroll
    for (int m = 32; m; m >>= 1) dot += __shfl_xor(dot, m);
    if (ln == 0) {
        diag[i] = dot;
        const int id = iid[i];
        tauIg[i] = tau_I[id];
        obI[i]   = b_I[id];
        const int td = tid_[i];
        tauTg[i] = tau_T[td];
        obT[i]   = b_T[td];
    }
}

// ---------------------------------------------------------------------------
// bf16 MFMA GEMM (m97 structure) + fused partial row/col max epilogue.
// 128x128 tile / block, 256 threads (4 waves), wave = 64x64 as 4x4 MFMA
// 16x16x32 tiles. global_load_lds width=16 staging, BK=32.
// Epilogue: rp[colchunk=bx][row] = max_j(sim) over this block's 128 cols,
//           cp[rowchunk=by][col] = max_i(sim) over this block's 128 rows.
// ---------------------------------------------------------------------------
__device__ __forceinline__ void async16(const void* g, void* l) {
    __builtin_amdgcn_global_load_lds(
        (const __attribute__((address_space(1))) void*)g,
        (__attribute__((address_space(3))) void*)l, 16, 0, 0);
}

__global__ __launch_bounds__(256) void gemm_bt_bf16(const unsigned short* __restrict__ A,
                                                    const unsigned short* __restrict__ B,
                                                    float* __restrict__ C,
                                                    float* __restrict__ rp,
                                                    float* __restrict__ cp) {
    __shared__ unsigned short As[128 * 32];   // [128][32] bf16, 8 KB
    __shared__ unsigned short Bs[128 * 32];

    const int tid  = threadIdx.x;
    const int lane = tid & 63;
    const int wave = tid >> 6;
    const int bi = blockIdx.y * 128;
    const int bj = blockIdx.x * 128;
    const int m_base = (wave >> 1) * 64;
    const int n_base = (wave & 1) * 64;

    const int c0 = tid, c1 = tid + 256;
    const int r0 = c0 >> 2, ko0 = (c0 & 3) * 8;
    const int r1 = c1 >> 2, ko1 = (c1 & 3) * 8;

    f32x4 acc[4][4];
#pragma unroll
    for (int m = 0; m < 4; ++m)
#pragma unroll
        for (int n = 0; n < 4; ++n)
            acc[m][n] = (f32x4){0.f, 0.f, 0.f, 0.f};

    const int mrow = lane & 15;
    const int kq   = (lane >> 4) * 8;

    for (int k0 = 0; k0 < DIM; k0 += 32) {
        __syncthreads();
        async16(&A[(size_t)(bi + r0) * DIM + k0 + ko0], &As[c0 * 8]);
        async16(&A[(size_t)(bi + r1) * DIM + k0 + ko1], &As[c1 * 8]);
        async16(&B[(size_t)(bj + r0) * DIM + k0 + ko0], &Bs[c0 * 8]);
        async16(&B[(size_t)(bj + r1) * DIM + k0 + ko1], &Bs[c1 * 8]);
        __syncthreads();

        bf16x8 af[4], bfr[4];
#pragma unroll
        for (int t = 0; t < 4; ++t) {
            af[t]  = *(const bf16x8*)&As[(m_base + t * 16 + mrow) * 32 + kq];
            bfr[t] = *(const bf16x8*)&Bs[(n_base + t * 16 + mrow) * 32 + kq];
        }
#pragma unroll
        for (int mt = 0; mt < 4; ++mt)
#pragma unroll
            for (int nt = 0; nt < 4; ++nt)
                acc[mt][nt] = __builtin_amdgcn_mfma_f32_16x16x32_bf16(
                    af[mt], bfr[nt], acc[mt][nt], 0, 0, 0);
    }

    // C/D layout: col = lane&15, row = (lane>>4)*4 + r   [m89 verified]
    const int col  = lane & 15;
    const int rowq = (lane >> 4) * 4;
#pragma unroll
    for (int mt = 0; mt < 4; ++mt)
#pragma unroll
        for (int nt = 0; nt < 4; ++nt)
#pragma unroll
            for (int r = 0; r < 4; ++r)
                C[(size_t)(bi + m_base + mt * 16 + rowq + r) * BSZ +
                  bj + n_base + nt * 16 + col] = acc[mt][nt][r];

    // ---- fused partial max epilogue ----
    // per-lane row maxes: row = m_base + mt*16 + (lane>>4)*4 + r, over 64 cols
    float rm[4][4];
#pragma unroll
    for (int mt = 0; mt < 4; ++mt)
#pragma unroll
        for (int r = 0; r < 4; ++r) {
            float v = fmaxf(fmaxf(acc[mt][0][r], acc[mt][1][r]),
                            fmaxf(acc[mt][2][r], acc[mt][3][r]));
#pragma unroll
            for (int m = 1; m <= 8; m <<= 1) v = fmaxf(v, __shfl_xor(v, m));
            rm[mt][r] = v;
        }
    // per-lane col maxes: col = n_base + nt*16 + (lane&15), over 64 rows
    float cm[4];
#pragma unroll
    for (int nt = 0; nt < 4; ++nt) {
        float v = -INFINITY;
#pragma unroll
        for (int mt = 0; mt < 4; ++mt)
#pragma unroll
            for (int r = 0; r < 4; ++r) v = fmaxf(v, acc[mt][nt][r]);
        v = fmaxf(v, __shfl_xor(v, 16));
        v = fmaxf(v, __shfl_xor(v, 32));
        cm[nt] = v;
    }
    __syncthreads();
    float* red = (float*)As;   // reuse LDS: [0..255]=row, [256..511]=col
    if ((lane & 15) == 0) {
        const int g = lane >> 4;
#pragma unroll
        for (int mt = 0; mt < 4; ++mt)
#pragma unroll
            for (int r = 0; r < 4; ++r)
                red[wave * 64 + mt * 16 + g * 4 + r] = rm[mt][r];
    }
    if (lane < 16) {
#pragma unroll
        for (int nt = 0; nt < 4; ++nt)
            red[256 + wave * 64 + nt * 16 + lane] = cm[nt];
    }
    __syncthreads();
    if (tid < 128) {
        const int row = tid;
        const int hi = (row >> 6) ? 1 : 0;          // waves {0,1} rows 0-63, {2,3} rows 64-127
        float v = fmaxf(red[(hi * 2) * 64 + (row & 63)],
                        red[(hi * 2 + 1) * 64 + (row & 63)]);
        rp[(size_t)blockIdx.x * BSZ + bi + row] = v;
    } else {
        const int colg = tid - 128;
        const int hi = (colg >> 6) ? 1 : 0;         // waves {0,2} cols 0-63, {1,3} cols 64-127
        float v = fmaxf(red[256 + hi * 64 + (colg & 63)],
                        red[256 + (hi + 2) * 64 + (colg & 63)]);
        cp[(size_t)blockIdx.y * BSZ + bj + colg] = v;
    }
}

// ---------------------------------------------------------------------------
// maxcombine: nbI[i] = max(obI, (max_j sim - diag)*itauI); likewise nbT.
// ---------------------------------------------------------------------------
__global__ __launch_bounds__(256) void maxcombine(const float* __restrict__ rp,
                                                  const float* __restrict__ cp,
                                                  const float* __restrict__ diag,
                                                  const float* __restrict__ tauIg,
                                                  const float* __restrict__ tauTg,
                                                  const float* __restrict__ obI,
                                                  const float* __restrict__ obT,
                                                  float* nbI, float* nbT) {
    const int i = blockIdx.x * 256 + threadIdx.x;
    if (i >= BSZ) return;
    float mr = -INFINITY, mc = -INFINITY;
#pragma unroll
    for (int k = 0; k < 32; ++k) {
        mr = fmaxf(mr, rp[(size_t)k * BSZ + i]);
        mc = fmaxf(mc, cp[(size_t)k * BSZ + i]);
    }
    const float dg = diag[i];
    nbI[i] = fmaxf(obI[i], (mr - dg) / tauIg[i]);
    nbT[i] = fmaxf(obT[i], (mc - dg) / tauTg[i]);
}

// ---------------------------------------------------------------------------
// fused_sum: ONE pass over sim producing both row partials (image side) and
// col partials (text side) of (sum e, sum e*v).
// Block: 64 cols x 4 row-waves; each block covers 64 cols x 256 rows.
// Grid: (64 colchunks, 16 rowchunks).
// ---------------------------------------------------------------------------
__global__ __launch_bounds__(256) void fused_sum(const float* __restrict__ sim,
                                                 const float* __restrict__ diag,
                                                 const float* __restrict__ tauIg,
                                                 const float* __restrict__ tauTg,
                                                 const float* __restrict__ nbI,
                                                 const float* __restrict__ nbT,
                                                 float* __restrict__ rpsE,
                                                 float* __restrict__ rpsEI,
                                                 float* __restrict__ cpsE,
                                                 float* __restrict__ cpsEI) {
    const int ln = threadIdx.x & 63;
    const int w  = threadIdx.x >> 6;
    const int c  = blockIdx.x * 64 + ln;
    const int rbeg = blockIdx.y * 256;

    __shared__ float sdg[256], sit[256], sb[256];
    {
        const int t = threadIdx.x;
        sdg[t] = diag[rbeg + t];
        sit[t] = 1.0f / tauIg[rbeg + t];
        sb[t]  = nbI[rbeg + t];
    }
    const float dgc = diag[c];
    const float itc = 1.0f / tauTg[c];
    const float bc  = nbT[c];
    __syncthreads();

    float ceT = 0.f, ceiT = 0.f;
    for (int lr = w; lr < 256; lr += 4) {
        const int r = rbeg + lr;
        const float s = sim[(size_t)r * BSZ + c];
        // image (row) side
        const float vI = (s - sdg[lr]) * sit[lr];
        const float eI = __expf(vI - sb[lr]);
        float se = eI, sei = eI * vI;
#pragma unroll
        for (int m = 1; m <= 32; m <<= 1) {
            se  += __shfl_xor(se, m);
            sei += __shfl_xor(sei, m);
        }
        if (ln == 0) {
            rpsE [(size_t)blockIdx.x * BSZ + r] = se;
            rpsEI[(size_t)blockIdx.x * BSZ + r] = sei;
        }
        // text (col) side
        const float vT = (s - dgc) * itc;
        const float eT = __expf(vT - bc);
        ceT  += eT;
        ceiT += eT * vT;
    }
    __shared__ float l1[4][64], l2[4][64];
    l1[w][ln] = ceT;
    l2[w][ln] = ceiT;
    __syncthreads();
    if (threadIdx.x < 64) {
        const int t = threadIdx.x;
        cpsE [(size_t)blockIdx.y * BSZ + blockIdx.x * 64 + t] =
            l1[0][t] + l1[1][t] + l1[2][t] + l1[3][t];
        cpsEI[(size_t)blockIdx.y * BSZ + blockIdx.x * 64 + t] =
            l2[0][t] + l2[1][t] + l2[2][t] + l2[3][t];
    }
}

// ---------------------------------------------------------------------------
// Copy 8 state arrays to output region (float4 main body, scalar edges).
// ---------------------------------------------------------------------------
__global__ __launch_bounds__(256) void copy_states(const float* __restrict__ s_I,
                                                   const float* __restrict__ s_T,
                                                   const float* __restrict__ u_I,
                                                   const float* __restrict__ u_T,
                                                   const float* __restrict__ b_I,
                                                   const float* __restrict__ b_T,
                                                   const float* __restrict__ tau_I,
                                                   const float* __restrict__ tau_T,
                                                   float* __restrict__ outbase) {
    const size_t idx = (size_t)blockIdx.x * blockDim.x + threadIdx.x;
    const size_t stride = (size_t)gridDim.x * blockDim.x;
    const size_t NV = (NST - 1) / 4;
    const float* srcs[8] = {s_I, s_T, u_I, u_T, b_I, b_T, tau_I, tau_T};
#pragma unroll
    for (int a = 0; a < 8; ++a) {
        const float* s = srcs[a];
        float* d = outbase + (size_t)a * NST;
        for (size_t cidx = idx; cidx < NV; cidx += stride) {
            const size_t e = 1 + 4 * cidx;
            float4 v = make_float4(s[e], s[e + 1], s[e + 2], s[e + 3]);
            *(float4*)&d[e] = v;
        }
        if (idx == 0) d[0] = s[0];
        if (idx < 3)  d[NST - 3 + idx] = s[NST - 3 + idx];
    }
}

// ---------------------------------------------------------------------------
// Finalize.
// ---------------------------------------------------------------------------
__global__ __launch_bounds__(256) void finalize(const float* __restrict__ s_I,
                                                const float* __restrict__ s_T,
                                                const float* __restrict__ u_I,
                                                const float* __restrict__ u_T,
                                                const int* __restrict__ iid,
                                                const int* __restrict__ tid_,
                                                const int* __restrict__ epoch,
                                                const int* __restrict__ maxep,
                                                const float* __restrict__ tauIg,
                                                const float* __restrict__ tauTg,
                                                const float* __restrict__ obI,
                                                const float* __restrict__ obT,
                                                const float* __restrict__ nbI,
                                                const float* __restrict__ nbT,
                                                const float* __restrict__ rpsE,
                                                const float* __restrict__ rpsEI,
                                                const float* __restrict__ cpsE,
                                                const float* __restrict__ cpsEI,
                                                float* __restrict__ out,
                                                float* __restrict__ ilo,
                                                float* __restrict__ tlo) {
    const int i = blockIdx.x * 256 + threadIdx.x;
    if (i >= BSZ) return;

    const float eta = ETA_MIN_C + (ETA_INIT_C - ETA_MIN_C) *
                      cosf(0.5f * PI_F * ((float)epoch[0] / (float)maxep[0]));
    const float invBm1 = 1.0f / (float)(BSZ - 1);

    float* o_gI   = out;
    float* o_gT   = out + BSZ;
    float* o_gti  = out + 2 * BSZ;
    float* o_gtt  = out + 3 * BSZ;
    float* o_sI   = out + 4 * BSZ + 3;
    float* o_sT   = o_sI + NST;
    float* o_uI   = o_sT + NST;
    float* o_uT   = o_uI + NST;
    float* o_bI   = o_uT + NST;
    float* o_bT   = o_bI + NST;
    float* o_tauI = o_bT + NST;
    float* o_tauT = o_tauI + NST;

    // image side
    {
        const int id = iid[i];
        float se = 0.f, sei = 0.f;
#pragma unroll
        for (int k = 0; k < 32; ++k) {
            se  += rpsE [(size_t)k * BSZ + i] + rpsE [(size_t)(k + 32) * BSZ + i];
            sei += rpsEI[(size_t)k * BSZ + i] + rpsEI[(size_t)(k + 32) * BSZ + i];
        }
        const float g = se * invBm1;
        const float ob = obI[i], nb = nbI[i];
        const float s_new = (1.f - GAMMA_S) * s_I[id] * __expf(ob - nb) + GAMMA_S * g;
        const float W = sei * invBm1 / (s_new + C_EPS);
        const float grad = logf(s_new) + nb + RHO_I_C - W;
        const float tau = tauIg[i];
        ilo[i] = tau * W;
        const float gc = fminf(fmaxf(grad, -GCLIP), GCLIP);
        const float u_new = (1.f - GAMMA_U) * u_I[id] + GAMMA_U * gc;
        const float tau_new = fminf(fmaxf(tau - eta * u_new, TAU_MIN_C), TAU_MAX_C);
        o_gI[i] = g;
        o_gti[i] = grad;
        o_sI[id] = s_new;
        o_uI[id] = u_new;
        o_bI[id] = nb;
        o_tauI[id] = tau_new;
    }
    // text side
    {
        const int id = tid_[i];
        float se = 0.f, sei = 0.f;
#pragma unroll
        for (int k = 0; k < 16; ++k) {
            se  += cpsE [(size_t)k * BSZ + i];
            sei += cpsEI[(size_t)k * BSZ + i];
        }
        const float g = se * invBm1;
        const float ob = obT[i], nb = nbT[i];
        const float s_new = (1.f - GAMMA_S) * s_T[id] * __expf(ob - nb) + GAMMA_S * g;
        const float W = sei * invBm1 / (s_new + C_EPS);
        const float grad = logf(s_new) + nb + RHO_T_C - W;
        const float tau = tauTg[i];
        tlo[i] = tau * W;
        const float gc = fminf(fmaxf(grad, -GCLIP), GCLIP);
        const float u_new = (1.f - GAMMA_U) * u_T[id] + GAMMA_U * gc;
        const float tau_new = fminf(fmaxf(tau - eta * u_new, TAU_MIN_C), TAU_MAX_C);
        o_gT[i] = g;
        o_gtt[i] = grad;
        o_sT[id] = s_new;
        o_uT[id] = u_new;
        o_bT[id] = nb;
        o_tauT[id] = tau_new;
    }
}

// ---------------------------------------------------------------------------
// Scalars: total_loss, avg taus.
// ---------------------------------------------------------------------------
__global__ __launch_bounds__(256) void scalar_out(const float* __restrict__ ilo,
                                                  const float* __restrict__ tlo,
                                                  const float* __restrict__ tauIg,
                                                  const float* __restrict__ tauTg,
                                                  float* __restrict__ out) {
    float s0 = 0.f, s1 = 0.f, s2 = 0.f, s3 = 0.f;
    for (int j = threadIdx.x; j < BSZ; j += 256) {
        s0 += ilo[j];
        s1 += tlo[j];
        s2 += tauIg[j];
        s3 += tauTg[j];
    }
#pragma unroll
    for (int o = 32; o; o >>= 1) {
        s0 += __shfl_down(s0, o);
        s1 += __shfl_down(s1, o);
        s2 += __shfl_down(s2, o);
        s3 += __shfl_down(s3, o);
    }
    __shared__ float lds[4][4];
    const int wv = threadIdx.x >> 6, ln = threadIdx.x & 63;
    if (ln == 0) { lds[wv][0] = s0; lds[wv][1] = s1; lds[wv][2] = s2; lds[wv][3] = s3; }
    __syncthreads();
    if (threadIdx.x == 0) {
        float t0 = lds[0][0] + lds[1][0] + lds[2][0] + lds[3][0];
        float t1 = lds[0][1] + lds[1][1] + lds[2][1] + lds[3][1];
        float t2 = lds[0][2] + lds[1][2] + lds[2][2] + lds[3][2];
        float t3 = lds[0][3] + lds[1][3] + lds[2][3] + lds[3][3];
        out[4 * BSZ + 0] = t0 / BSZ + t1 / BSZ;
        out[4 * BSZ + 1] = t2 / BSZ;
        out[4 * BSZ + 2] = t3 / BSZ;
    }
}

// ---------------------------------------------------------------------------
extern "C" void kernel_launch(void* const* d_in, const int* in_sizes, int n_in,
                              void* d_out, int out_size, void* d_ws, size_t ws_size,
                              hipStream_t stream) {
    const float* imf   = (const float*)d_in[0];
    const float* txf   = (const float*)d_in[1];
    const float* s_I   = (const float*)d_in[2];
    const float* s_T   = (const float*)d_in[3];
    const float* tau_I = (const float*)d_in[4];
    const float* tau_T = (const float*)d_in[5];
    const float* u_I   = (const float*)d_in[6];
    const float* u_T   = (const float*)d_in[7];
    const float* b_I   = (const float*)d_in[8];
    const float* b_T   = (const float*)d_in[9];
    const int* iid     = (const int*)d_in[10];
    const int* tid_    = (const int*)d_in[11];
    const int* epoch   = (const int*)d_in[12];
    const int* maxep   = (const int*)d_in[13];

    float* out = (float*)d_out;
    float* ws  = (float*)d_ws;

    float* sim  = ws;
    float* aux  = ws + (size_t)BSZ * BSZ;
    float* diag  = aux + 0 * BSZ;
    float* tauIg = aux + 1 * BSZ;
    float* tauTg = aux + 2 * BSZ;
    float* obI   = aux + 3 * BSZ;
    float* obT   = aux + 4 * BSZ;
    float* nbI   = aux + 5 * BSZ;
    float* nbT   = aux + 6 * BSZ;
    float* ilo   = aux + 7 * BSZ;
    float* tlo   = aux + 8 * BSZ;
    float* rp    = aux + 9 * BSZ;                  // 32 * BSZ
    float* cp    = rp + (size_t)32 * BSZ;          // 32 * BSZ
    float* rpsE  = cp + (size_t)32 * BSZ;          // 64 * BSZ
    float* rpsEI = rpsE + (size_t)64 * BSZ;        // 64 * BSZ
    float* cpsE  = rpsEI + (size_t)64 * BSZ;       // 16 * BSZ
    float* cpsEI = cpsE + (size_t)16 * BSZ;        // 16 * BSZ
    unsigned short* abf = (unsigned short*)(cpsEI + (size_t)16 * BSZ);
    unsigned short* bbf = abf + (size_t)BSZ * DIM;

    conv_diag<<<BSZ / 4, 256, 0, stream>>>(imf, txf, abf, bbf, tau_I, tau_T, b_I, b_T,
                                           iid, tid_, diag, tauIg, tauTg, obI, obT);
    dim3 gg(BSZ / 128, BSZ / 128);
    gemm_bt_bf16<<<gg, 256, 0, stream>>>(abf, bbf, sim, rp, cp);
    maxcombine<<<BSZ / 256, 256, 0, stream>>>(rp, cp, diag, tauIg, tauTg, obI, obT,
                                              nbI, nbT);
    fused_sum<<<dim3(BSZ / 64, BSZ / 256), 256, 0, stream>>>(sim, diag, tauIg, tauTg,
                                                             nbI, nbT,
                                                             rpsE, rpsEI, cpsE, cpsEI);
    copy_states<<<4096, 256, 0, stream>>>(s_I, s_T, u_I, u_T, b_I, b_T, tau_I, tau_T,
                                          out + 4 * BSZ + 3);
    finalize<<<BSZ / 256, 256, 0, stream>>>(s_I, s_T, u_I, u_T, iid, tid_, epoch, maxep,
                                            tauIg, tauTg, obI, obT, nbI, nbT,
                                            rpsE, rpsEI, cpsE, cpsEI, out, ilo, tlo);
    scalar_out<<<1, 256, 0, stream>>>(ilo, tlo, tauIg, tauTg, out);
}